// Round 2
// baseline (1145.134 us; speedup 1.0000x reference)
//
#include <hip/hip_runtime.h>

#define HW 4096
#define CC 256
#define KK 2048
#define BB 16
#define NN (BB*HW)          // 65536
#define ROWS 16

// d_out layout (floats): [z_q 16777216][idx 65536][loss 1][probs 134217728]
#define ZQ_SZ   (BB*CC*HW)          // 16777216
#define IDX_OFF ZQ_SZ
#define LOSS_OFF (IDX_OFF + NN)     // 16842752
#define PROBS_OFF (LOSS_OFF + 1)    // 16842753 (only 4B-aligned!)
// scratch parked inside the z_q region (overwritten by k_zq at the end):
#define CT_OFF 0                    // ct[C][K] transposed codebook, 2MB
#define EE_OFF (CC*KK)              // ee[K]
#define ZZ_OFF 1048576              // zz[N]

// ---- numpy pairwise sum-of-squares over 256 elements (PW_BLOCKSIZE=128) ----
// replicates: np.sum(x*x) for contiguous n=256: pairwise(0:128) + pairwise(128:256),
// each half: 8 scalar accumulators, combine ((r0+r1)+(r2+r3))+((r4+r5)+(r6+r7)).
// __fmul_rn/__fadd_rn block fma-contraction so mul and add round separately (as numpy).
template<int STRIDE>
__device__ __forceinline__ float np_sumsq256(const float* __restrict__ a){
  float res0 = 0.f, res1 = 0.f;
  #pragma unroll
  for (int h = 0; h < 2; h++){
    const float* p = a + (size_t)h * 128 * STRIDE;
    float r[8];
    #pragma unroll
    for (int j = 0; j < 8; j++){ float x = p[(size_t)j * STRIDE]; r[j] = __fmul_rn(x, x); }
    for (int i = 8; i < 128; i += 8){
      #pragma unroll
      for (int j = 0; j < 8; j++){
        float x = p[(size_t)(i + j) * STRIDE];
        r[j] = __fadd_rn(r[j], __fmul_rn(x, x));
      }
    }
    float s = __fadd_rn(__fadd_rn(__fadd_rn(r[0], r[1]), __fadd_rn(r[2], r[3])),
                        __fadd_rn(__fadd_rn(r[4], r[5]), __fadd_rn(r[6], r[7])));
    if (h == 0) res0 = s; else res1 = s;
  }
  return __fadd_rn(res0, res1);
}

// ---------------- codebook transpose: ct[c][k] = cb[k][c] ----------------
__global__ void k_prep(const float* __restrict__ cb, float* __restrict__ out){
  __shared__ float tile[64][65];
  const int t = threadIdx.x;            // 256
  const int lane = t & 63, q = t >> 6;
  const int bk = blockIdx.x & 31;
  const int bc = blockIdx.x >> 5;
  const int k0 = bk * 64, c0 = bc * 64;
  #pragma unroll
  for (int j = 0; j < 16; j++){
    int kr = q * 16 + j;
    tile[kr][lane] = cb[(size_t)(k0 + kr) * CC + c0 + lane];
  }
  __syncthreads();
  float* ct = out + CT_OFF;
  #pragma unroll
  for (int j = 0; j < 16; j++){
    int cr = q * 16 + j;
    ct[(size_t)(c0 + cr) * KK + k0 + lane] = tile[lane][cr];
  }
}

// ---------------- ee[k] = np-pairwise sum_c cb[k][c]^2 ----------------
__global__ void k_ee(const float* __restrict__ cb, float* __restrict__ out){
  const int k = blockIdx.x * 256 + threadIdx.x;  // 8 blocks -> 2048
  out[EE_OFF + k] = np_sumsq256<1>(cb + (size_t)k * CC);
}

// ---------------- zz[n] = np-pairwise sum_c feats[b][c][hw]^2 ----------------
__global__ void k_zz(const float* __restrict__ feats, float* __restrict__ out){
  const int n = blockIdx.x * 256 + threadIdx.x;  // 256 blocks -> 65536
  const int b = n >> 12, hw = n & 4095;
  out[ZZ_OFF + n] = np_sumsq256<HW>(feats + (size_t)b * CC * HW + hw);
}

// ---------------- main: d (np-fp32-bit-exact), argmin, softmax probs, loss ----------------
__global__ __launch_bounds__(512, 4)
void k_main(const float* __restrict__ feats, const float* __restrict__ cb, float* out){
  __shared__ float zt[CC][ROWS];     // z staged transposed, 16KB
  __shared__ float zzs[ROWS];
  __shared__ float minv_s[ROWS];
  __shared__ float red_v[ROWS][8];
  __shared__ int   red_k[ROWS][8];
  __shared__ float red_s[ROWS][8];
  __shared__ float sum_s[ROWS];
  __shared__ int   finidx[ROWS];
  __shared__ float lred[ROWS];

  const int t   = threadIdx.x;
  const int blk = blockIdx.x;          // 4096
  const int bi  = blk >> 8;            // image index
  const int hw0 = (blk & 255) * ROWS;  // pixel base
  const int row0 = bi * HW + hw0;
  const int wv = t >> 6, lane = t & 63;

  // ---- stage z rows: zt[c][r] = feats[bi][c][hw0+r]
  {
    int c = t >> 1, half = t & 1;
    const float* src = feats + (size_t)(bi * CC + c) * HW + hw0 + half * 8;
    float4 a = *(const float4*)src;
    float4 b = *(const float4*)(src + 4);
    float* dst = &zt[c][half * 8];
    *(float4*)dst = a; *(float4*)(dst + 4) = b;
  }
  if (t < ROWS) zzs[t] = out[ZZ_OFF + row0 + t];   // np-exact ||z||^2
  __syncthreads();

  // ---- fp32 GEMM, sequential-c FMA chain per (row,k) — matches CPU sgemm microkernel
  const float* ct = out + CT_OFF;
  const int k0 = t * 4;
  float acc[ROWS][4];
  #pragma unroll
  for (int r = 0; r < ROWS; r++){ acc[r][0]=0.f; acc[r][1]=0.f; acc[r][2]=0.f; acc[r][3]=0.f; }

  const float* ctp = ct + k0;
  #pragma unroll 2
  for (int c = 0; c < CC; c++){
    const float4 cv = *(const float4*)(ctp + (size_t)c * KK);
    #pragma unroll
    for (int j = 0; j < 4; j++){
      const float4 zv = *(const float4*)&zt[c][j * 4];
      acc[j*4+0][0] = __builtin_fmaf(zv.x, cv.x, acc[j*4+0][0]);
      acc[j*4+0][1] = __builtin_fmaf(zv.x, cv.y, acc[j*4+0][1]);
      acc[j*4+0][2] = __builtin_fmaf(zv.x, cv.z, acc[j*4+0][2]);
      acc[j*4+0][3] = __builtin_fmaf(zv.x, cv.w, acc[j*4+0][3]);
      acc[j*4+1][0] = __builtin_fmaf(zv.y, cv.x, acc[j*4+1][0]);
      acc[j*4+1][1] = __builtin_fmaf(zv.y, cv.y, acc[j*4+1][1]);
      acc[j*4+1][2] = __builtin_fmaf(zv.y, cv.z, acc[j*4+1][2]);
      acc[j*4+1][3] = __builtin_fmaf(zv.y, cv.w, acc[j*4+1][3]);
      acc[j*4+2][0] = __builtin_fmaf(zv.z, cv.x, acc[j*4+2][0]);
      acc[j*4+2][1] = __builtin_fmaf(zv.z, cv.y, acc[j*4+2][1]);
      acc[j*4+2][2] = __builtin_fmaf(zv.z, cv.z, acc[j*4+2][2]);
      acc[j*4+2][3] = __builtin_fmaf(zv.z, cv.w, acc[j*4+2][3]);
      acc[j*4+3][0] = __builtin_fmaf(zv.w, cv.x, acc[j*4+3][0]);
      acc[j*4+3][1] = __builtin_fmaf(zv.w, cv.y, acc[j*4+3][1]);
      acc[j*4+3][2] = __builtin_fmaf(zv.w, cv.z, acc[j*4+3][2]);
      acc[j*4+3][3] = __builtin_fmaf(zv.w, cv.w, acc[j*4+3][3]);
    }
  }

  // ---- d = fl(fl(zz+ee) - 2*dot): matches numpy's two elementwise roundings
  // (2*acc is exact, so fl(t1 - 2*acc) is deterministic w/ or w/o contraction)
  const float4 eev = *(const float4*)(out + EE_OFF + k0);
  #pragma unroll
  for (int r = 0; r < ROWS; r++){
    const float zr = zzs[r];
    acc[r][0] = __fadd_rn(__fadd_rn(zr, eev.x), -2.f * acc[r][0]);
    acc[r][1] = __fadd_rn(__fadd_rn(zr, eev.y), -2.f * acc[r][1]);
    acc[r][2] = __fadd_rn(__fadd_rn(zr, eev.z), -2.f * acc[r][2]);
    acc[r][3] = __fadd_rn(__fadd_rn(zr, eev.w), -2.f * acc[r][3]);
  }

  // ---- per-row fp32 min+argmin, lowest-k ties (= numpy first-index)
  #pragma unroll
  for (int r = 0; r < ROWS; r++){
    float v = acc[r][0]; int kk = k0;
    if (acc[r][1] < v){ v = acc[r][1]; kk = k0 + 1; }
    if (acc[r][2] < v){ v = acc[r][2]; kk = k0 + 2; }
    if (acc[r][3] < v){ v = acc[r][3]; kk = k0 + 3; }
    #pragma unroll
    for (int off = 32; off; off >>= 1){
      float v2 = __shfl_xor(v, off);
      int   k2 = __shfl_xor(kk, off);
      if (v2 < v || (v2 == v && k2 < kk)){ v = v2; kk = k2; }
    }
    if (lane == 0){ red_v[r][wv] = v; red_k[r][wv] = kk; }
  }
  __syncthreads();
  if (t < ROWS){
    float v = red_v[t][0]; int kk = red_k[t][0];
    #pragma unroll
    for (int j = 1; j < 8; j++){
      float v2 = red_v[t][j]; int k2 = red_k[t][j];
      if (v2 < v || (v2 == v && k2 < kk)){ v = v2; kk = k2; }
    }
    minv_s[t] = v; finidx[t] = kk;
  }
  __syncthreads();

  // ---- softmax(-|d|): d>0 here so = exp(min-d); row sums
  #pragma unroll
  for (int r = 0; r < ROWS; r++){
    float m = minv_s[r];
    float s = 0.f;
    #pragma unroll
    for (int i = 0; i < 4; i++){
      float e = __expf(m - acc[r][i]);
      acc[r][i] = e; s += e;
    }
    #pragma unroll
    for (int off = 32; off; off >>= 1) s += __shfl_xor(s, off);
    if (lane == 0) red_s[r][wv] = s;
  }
  __syncthreads();
  if (t < ROWS){
    float s = 0.f;
    #pragma unroll
    for (int j = 0; j < 8; j++) s += red_s[t][j];
    sum_s[t] = s;
  }
  __syncthreads();

  // ---- idx output (as float)
  if (t < ROWS) out[IDX_OFF + row0 + t] = (float)finidx[t];

  // ---- probs output: out[bi][k][hw0+r] (region only 4B-aligned -> scalar stores)
  float inv[ROWS];
  #pragma unroll
  for (int r = 0; r < ROWS; r++) inv[r] = 1.f / sum_s[r];
  #pragma unroll
  for (int i = 0; i < 4; i++){
    size_t base = (size_t)PROBS_OFF + (size_t)(bi * KK + k0 + i) * HW + hw0;
    #pragma unroll
    for (int r = 0; r < ROWS; r++){
      out[base + r] = acc[r][i] * inv[r];
    }
  }

  // ---- loss partial: sum (cb[idx]-z)^2, one atomic per block, pre-scaled
  {
    int r = t >> 5, part = t & 31;
    const float* crow = cb + (size_t)finidx[r] * CC;
    float s = 0.f;
    for (int c = part; c < CC; c += 32){
      float d = crow[c] - zt[c][r];
      s += d * d;
    }
    #pragma unroll
    for (int off = 16; off; off >>= 1) s += __shfl_xor(s, off);
    if (part == 0) lred[r] = s;
  }
  __syncthreads();
  if (t == 0){
    float s = 0.f;
    #pragma unroll
    for (int r = 0; r < ROWS; r++) s += lred[r];
    atomicAdd(out + LOSS_OFF, s * (1.25f / 16777216.f));
  }
}

// ---------------- z_q gather: out[b][c][hw] = cb[idx[b,hw]][c] (bit-exact copy) ----------------
__global__ void k_zq(const float* __restrict__ cb, float* __restrict__ out){
  const int f4 = blockIdx.x * 256 + threadIdx.x;  // 16384 blocks
  const int f = f4 * 4;
  const int b = f >> 20;
  const int rem = f & 1048575;
  const int c = rem >> 12;
  const int hw = rem & 4095;
  const int n = b * HW + hw;
  const float* idxf = out + IDX_OFF;
  float4 iv = *(const float4*)(idxf + n);
  float4 o;
  o.x = cb[(size_t)((int)iv.x) * CC + c];
  o.y = cb[(size_t)((int)iv.y) * CC + c];
  o.z = cb[(size_t)((int)iv.z) * CC + c];
  o.w = cb[(size_t)((int)iv.w) * CC + c];
  *(float4*)(out + f) = o;
}

extern "C" void kernel_launch(void* const* d_in, const int* in_sizes, int n_in,
                              void* d_out, int out_size, void* d_ws, size_t ws_size,
                              hipStream_t stream){
  const float* feats = (const float*)d_in[0];
  const float* cb    = (const float*)d_in[1];
  float* out = (float*)d_out;

  hipMemsetAsync(out + LOSS_OFF, 0, sizeof(float), stream);   // zero loss accumulator
  hipLaunchKernelGGL(k_prep, dim3(128),   dim3(256), 0, stream, cb, out);
  hipLaunchKernelGGL(k_ee,   dim3(8),     dim3(256), 0, stream, cb, out);
  hipLaunchKernelGGL(k_zz,   dim3(256),   dim3(256), 0, stream, feats, out);
  hipLaunchKernelGGL(k_main, dim3(4096),  dim3(512), 0, stream, feats, cb, out);
  hipLaunchKernelGGL(k_zq,   dim3(16384), dim3(256), 0, stream, cb, out);
}